// Round 4
// baseline (280.113 us; speedup 1.0000x reference)
//
#include <hip/hip_runtime.h>

#define NROWS 262144
#define NCOLS 128
#define TPB 256
#define WPB (TPB / 64)
#define NBLOCKS 4096
#define NWAVES (NBLOCKS * WPB)           // 16384 waves
#define NPAIRS (NROWS / 2)               // 131072
#define U 2                              // pairs per batch (kept for mapping)
#define NBATCH (NPAIRS / (NWAVES * U))   // 4 batches per wave
#define NP (NBATCH * U)                  // 8 pairs per wave, all in regs

typedef float floatx4 __attribute__((ext_vector_type(4)));

__device__ __forceinline__ floatx4 load4(const float* p)
{
    return *(const floatx4*)p;
}

// Lanes 0-31 -> row 2p, lanes 32-63 -> row 2p+1; each lane loads one float4
// of x and t per pair (wave covers 1KB contiguous per array per pair).
//
// R4: the R3 counters showed VGPR_Count=28 < the 32 data regs needed for even
// one batch -- the compiler had silently de-pipelined the loop (loads sunk to
// just-before-use, MLP ~2). Fix: all 16 loads (8 pairs x 2 arrays) issued
// upfront and PINNED with sched_barrier(0), forcing ~64 data VGPRs live and
// ~16 loads/wave in flight. Pair set, processing order, and all arithmetic
// are identical to R3 (absmax 0.0) -- only load issue order changed.
__global__ __launch_bounds__(TPB) void biased_loss_partial(
    const float* __restrict__ x, const float* __restrict__ t,
    float* __restrict__ partial)
{
    const int lane = threadIdx.x & 63;
    const int waveInBlock = threadIdx.x >> 6;
    const int gw = blockIdx.x * WPB + waveInBlock;
    const int half = lane >> 5;
    const int sub  = lane & 31;
    const int c    = sub * 4;

    const size_t laneoff = (size_t)half * NCOLS + (size_t)c;

    floatx4 xv[NP], tv[NP];

    // Issue ALL loads back-to-back. Pair index p(b,u) = (b*NWAVES+gw)*U + u
    // -- exactly the same pairs, in the same array slots, as R3.
    #pragma unroll
    for (int b = 0; b < NBATCH; ++b) {
        #pragma unroll
        for (int u = 0; u < U; ++u) {
            const size_t base =
                (size_t)(2 * ((size_t)(b * NWAVES + gw) * U + u)) * NCOLS
                + laneoff;
            xv[b * U + u] = load4(x + base);
            tv[b * U + u] = load4(t + base);
        }
    }
    // Nothing may be scheduled across this point: loads cannot sink into the
    // compute, so all 16 stay in flight (consumption drains via partial
    // vmcnt(N) waits the compiler emits per use).
    __builtin_amdgcn_sched_barrier(0);

    float acc = 0.0f;

    #pragma unroll
    for (int i = 0; i < NP; ++i) {
        // lane-local max of this lane's 4 columns (value only)
        const float lm = fmaxf(fmaxf(xv[i].x, xv[i].y),
                               fmaxf(xv[i].z, xv[i].w));

        // butterfly max across the 32-lane half -> M in every lane
        float M = lm;
        #pragma unroll
        for (int off = 16; off > 0; off >>= 1)
            M = fmaxf(M, __shfl_xor(M, off, 64));

        // t at the first column of THIS lane achieving M (garbage unless
        // this lane holds a match)
        const float tb_local = (xv[i].x == M) ? tv[i].x :
                               (xv[i].y == M) ? tv[i].y :
                               (xv[i].z == M) ? tv[i].z : tv[i].w;

        // first lane within this half whose columns contain M == the lane
        // that held the first-occurrence argmax
        const unsigned long long mask = __ballot(lm == M);
        const unsigned int mh = (unsigned int)(mask >> (half << 5));
        const int L = (half << 5) + (__ffs(mh) - 1);

        const float x0 = __shfl(xv[i].x, half << 5, 64);
        const float t0 = __shfl(tv[i].x, half << 5, 64);
        // argmax>0 <=> first occurrence of M is not column 0 <=> x0 != M
        const bool cond = (x0 != M) && (t0 == 0.0f);

        float s;
        if (cond) {
            // only the first-matching lane contributes; fabs(M)*t ==
            // fabs(M*t) bit-exactly (t is 0.0 or 1.0, signs preserved)
            s = (lane == L) ? fabsf(M) * tb_local : 0.0f;
        } else {
            const float c0 = fabsf(xv[i].x * tv[i].x);
            const float c1 = fabsf(xv[i].y * tv[i].y);
            const float c2 = fabsf(xv[i].z * tv[i].z);
            const float c3 = fabsf(xv[i].w * tv[i].w);
            s = (c0 + c1) + (c2 + c3);
        }
        acc += s;
    }

    // full-wave sum
    #pragma unroll
    for (int off = 32; off > 0; off >>= 1)
        acc += __shfl_xor(acc, off, 64);

    __shared__ float smem[WPB];
    if (lane == 0) smem[waveInBlock] = acc;
    __syncthreads();
    if (threadIdx.x == 0) {
        float bsum = 0.0f;
        #pragma unroll
        for (int w = 0; w < WPB; ++w) bsum += smem[w];
        partial[blockIdx.x] = bsum;
    }
}

__global__ __launch_bounds__(256) void reduce_partials(
    const float* __restrict__ partial, float* __restrict__ out, int n)
{
    float acc = 0.0f;
    for (int i = threadIdx.x; i < n; i += 256) acc += partial[i];
    #pragma unroll
    for (int off = 32; off > 0; off >>= 1)
        acc += __shfl_xor(acc, off, 64);
    __shared__ float smem[4];
    const int lane = threadIdx.x & 63, w = threadIdx.x >> 6;
    if (lane == 0) smem[w] = acc;
    __syncthreads();
    if (threadIdx.x == 0) {
        float s = smem[0] + smem[1] + smem[2] + smem[3];
        out[0] = s / (float)((size_t)NROWS * (size_t)NCOLS);
    }
}

extern "C" void kernel_launch(void* const* d_in, const int* in_sizes, int n_in,
                              void* d_out, int out_size, void* d_ws, size_t ws_size,
                              hipStream_t stream) {
    const float* x = (const float*)d_in[0];
    const float* t = (const float*)d_in[1];
    float* partial = (float*)d_ws;  // NBLOCKS * 4 B = 16 KiB scratch

    biased_loss_partial<<<NBLOCKS, TPB, 0, stream>>>(x, t, partial);
    reduce_partials<<<1, 256, 0, stream>>>(partial, (float*)d_out, NBLOCKS);
}